// Round 5
// baseline (86.304 us; speedup 1.0000x reference)
//
#include <hip/hip_runtime.h>

typedef __attribute__((ext_vector_type(8))) __bf16 bf16x8;
typedef __attribute__((ext_vector_type(4))) float f32x4;
typedef __attribute__((ext_vector_type(4))) int i32x4;

constexpr int Bn = 8192, Nn = 256, M1n = 128, M2n = 64, Mn = 192, ITERS = 30;
constexpr float TAUc = 0.05f, SIGc = 0.05f;

__device__ __forceinline__ ushort f2bf(float f) {
  unsigned u = __builtin_bit_cast(unsigned, f);
  u = (u + 0x7FFFu + ((u >> 16) & 1u)) >> 16;
  return (ushort)u;
}

// packed f32->bf16 (RNE), 2 values per instruction
__device__ __forceinline__ unsigned cvtpk(float lo, float hi) {
  unsigned r;
  asm("v_cvt_pk_bf16_f32 %0, %1, %2" : "=v"(r) : "v"(lo), "v"(hi));
  return r;
}

// Pin a fragment into AGPRs (accumulator file) - the VGPR spiller leaves it alone.
__device__ __forceinline__ void pina(i32x4& v) { asm volatile("" : "+a"(v)); }

// MFMA with B-operand read directly from AGPRs (gfx950: A/B may be VGPR or AGPR).
__device__ __forceinline__ void mfma_ab(f32x4& acc, bf16x8 a, i32x4 b) {
  asm("v_mfma_f32_16x16x32_bf16 %0, %1, %2, %0" : "+v"(acc) : "v"(a), "a"(b));
}

// Build bf16 copies of A = [A1;A2] in both orientations:
// Arm[m][n] (192x256 row-major), AT[n][m] (256x192 row-major).
__global__ void prep_kernel(const float* __restrict__ A1, const float* __restrict__ A2,
                            ushort* __restrict__ Arm, ushort* __restrict__ AT) {
  int i = blockIdx.x * 256 + threadIdx.x;
  if (i >= Mn * Nn) return;
  int m = i / Nn, n = i % Nn;
  float v = (m < M1n) ? A1[m * Nn + n] : A2[(m - M1n) * Nn + n];
  ushort b = f2bf(v);
  Arm[m * Nn + n] = b;
  AT[n * Mn + m] = b;
}

// 4 waves per block, TWO 16-row bands per block (32 rows). grid = 256 = 1 block/CU.
// Wave w owns: GEMM-1 m-tiles {3w,3w+1,3w+2}; GEMM-3 n-tiles {4w..4w+3}.
// 48 A-fragments pinned in AGPRs (192 AGPR), reused across both bands and all iters.
__global__ __launch_bounds__(256, 1) void pdhg_kernel(
    const float* __restrict__ x0, const float* __restrict__ y10,
    const float* __restrict__ y20, const float* __restrict__ z,
    const float* __restrict__ c, const ushort* __restrict__ Arm,
    const ushort* __restrict__ AT, float* __restrict__ out) {
  __shared__ __align__(16) ushort xb_lds[2][16][264];  // xbar bands (bf16)
  __shared__ __align__(16) ushort y_lds[2][16][200];   // y bands (bf16)
  __shared__ float z_lds[32][201];                     // sigma*z (f32)

  const int lane = threadIdx.x & 63;
  const int w = threadIdx.x >> 6;     // wave 0..3
  const int fr = lane & 15;           // fragment row (A-op) / col (B-op, C/D)
  const int kg = lane >> 4;           // k-group 0..3
  const int row0 = blockIdx.x * 32;   // this block's 32-row super-band

  // ---- stage sigma*z cooperatively (32 rows x 192)
  for (int idx = threadIdx.x; idx < 32 * Mn; idx += 256) {
    int r = idx / Mn, m = idx - r * Mn;
    z_lds[r][m] = SIGc * z[(row0 + r) * Mn + m];
  }

  float x[2][4][4], cv[4], ys[2][3][4];

  // ---- init x state + initial xbar = x0 into LDS (both bands)
#pragma unroll
  for (int t = 0; t < 4; ++t) {
    int n = (4 * w + t) * 16 + fr;
    cv[t] = c[n];
#pragma unroll
    for (int b = 0; b < 2; ++b)
#pragma unroll
      for (int g = 0; g < 4; ++g) {
        float v = x0[(row0 + 16 * b + kg * 4 + g) * Nn + n];
        x[b][t][g] = v;
        xb_lds[b][kg * 4 + g][n] = f2bf(v);
      }
  }
  // ---- init y state (registers)
#pragma unroll
  for (int i = 0; i < 3; ++i) {
    int m = (3 * w + i) * 16 + fr;
#pragma unroll
    for (int b = 0; b < 2; ++b)
#pragma unroll
      for (int g = 0; g < 4; ++g) {
        int r = row0 + 16 * b + kg * 4 + g;
        ys[b][i][g] = (m < M1n) ? y10[r * M1n + m] : y20[r * M2n + (m - M1n)];
      }
  }

  // ---- preload loop-invariant A fragments into AGPRs (48 frags = 192 AGPR)
  i32x4 armF[3][8], atF[4][6];
#pragma unroll
  for (int i = 0; i < 3; ++i) {
    int m = (3 * w + i) * 16 + fr;
#pragma unroll
    for (int kf = 0; kf < 8; ++kf) {
      armF[i][kf] = *reinterpret_cast<const i32x4*>(&Arm[m * Nn + kf * 32 + kg * 8]);
      pina(armF[i][kf]);
    }
  }
#pragma unroll
  for (int t = 0; t < 4; ++t) {
    int n = (4 * w + t) * 16 + fr;
#pragma unroll
    for (int kf = 0; kf < 6; ++kf) {
      atF[t][kf] = *reinterpret_cast<const i32x4*>(&AT[n * Mn + kf * 32 + kg * 8]);
      pina(atF[t][kf]);
    }
  }

  __syncthreads();

  for (int it = 0; it < ITERS; ++it) {
    // ---- GEMM-1: S = xbar @ A^T  (3 m-tiles x 2 bands; fx from LDS)
    bf16x8 fx[2][8];
#pragma unroll
    for (int b = 0; b < 2; ++b)
#pragma unroll
      for (int kf = 0; kf < 8; ++kf)
        fx[b][kf] = *reinterpret_cast<const bf16x8*>(&xb_lds[b][fr][kf * 32 + kg * 8]);

    f32x4 accA[2][3];
#pragma unroll
    for (int b = 0; b < 2; ++b)
#pragma unroll
      for (int i = 0; i < 3; ++i) accA[b][i] = f32x4{0.f, 0.f, 0.f, 0.f};
#pragma unroll
    for (int kf = 0; kf < 8; ++kf)
#pragma unroll
      for (int b = 0; b < 2; ++b)
#pragma unroll
        for (int i = 0; i < 3; ++i)
          mfma_ab(accA[b][i], fx[b][kf], armF[i][kf]);

    // ---- y update (f32 reg state), write bf16 Y bands to LDS
#pragma unroll
    for (int i = 0; i < 3; ++i) {
      int mt = 3 * w + i;
      int m = mt * 16 + fr;
#pragma unroll
      for (int b = 0; b < 2; ++b) {
#pragma unroll
        for (int g = 0; g < 4; ++g) {
          float s = __builtin_fmaf(SIGc, accA[b][i][g], ys[b][i][g]) - z_lds[16 * b + kg * 4 + g][m];
          if (mt < 8) s = fmaxf(s, 0.f);  // m-tiles 0..7 -> y1 relu
          ys[b][i][g] = s;
        }
        unsigned p01 = cvtpk(ys[b][i][0], ys[b][i][1]);
        unsigned p23 = cvtpk(ys[b][i][2], ys[b][i][3]);
        y_lds[b][kg * 4 + 0][m] = (ushort)p01;
        y_lds[b][kg * 4 + 1][m] = (ushort)(p01 >> 16);
        y_lds[b][kg * 4 + 2][m] = (ushort)p23;
        y_lds[b][kg * 4 + 3][m] = (ushort)(p23 >> 16);
      }
    }
    __syncthreads();

    // ---- GEMM-3: G = y @ A  (4 n-tiles x 2 bands; fy from LDS)
    bf16x8 fy[2][6];
#pragma unroll
    for (int b = 0; b < 2; ++b)
#pragma unroll
      for (int kf = 0; kf < 6; ++kf)
        fy[b][kf] = *reinterpret_cast<const bf16x8*>(&y_lds[b][fr][kf * 32 + kg * 8]);

    f32x4 accB[2][4];
#pragma unroll
    for (int b = 0; b < 2; ++b)
#pragma unroll
      for (int t = 0; t < 4; ++t) accB[b][t] = f32x4{0.f, 0.f, 0.f, 0.f};
#pragma unroll
    for (int kf = 0; kf < 6; ++kf)
#pragma unroll
      for (int b = 0; b < 2; ++b)
#pragma unroll
        for (int t = 0; t < 4; ++t)
          mfma_ab(accB[b][t], fy[b][kf], atF[t][kf]);

    // ---- x update (f32 reg state), write bf16 xbar to LDS
    const bool notlast = (it != ITERS - 1);
#pragma unroll
    for (int t = 0; t < 4; ++t) {
      int n = (4 * w + t) * 16 + fr;
#pragma unroll
      for (int b = 0; b < 2; ++b) {
        float xb[4];
#pragma unroll
        for (int g = 0; g < 4; ++g) {
          float grad = cv[t] + accB[b][t][g];
          float xn = fmaxf(__builtin_fmaf(-TAUc, grad, x[b][t][g]), 0.f);
          xb[g] = 2.f * xn - x[b][t][g];  // theta = 1
          x[b][t][g] = xn;
        }
        if (notlast) {
          unsigned p01 = cvtpk(xb[0], xb[1]);
          unsigned p23 = cvtpk(xb[2], xb[3]);
          xb_lds[b][kg * 4 + 0][n] = (ushort)p01;
          xb_lds[b][kg * 4 + 1][n] = (ushort)(p01 >> 16);
          xb_lds[b][kg * 4 + 2][n] = (ushort)p23;
          xb_lds[b][kg * 4 + 3][n] = (ushort)(p23 >> 16);
        }
      }
    }
    if (notlast) __syncthreads();
  }

  // ---- store outputs: x (B x 256), y1 (B x 128), y2 (B x 64), all f32
  float* ox = out;
  float* oy1 = out + Bn * Nn;
  float* oy2 = oy1 + Bn * M1n;
#pragma unroll
  for (int t = 0; t < 4; ++t) {
    int n = (4 * w + t) * 16 + fr;
#pragma unroll
    for (int b = 0; b < 2; ++b)
#pragma unroll
      for (int g = 0; g < 4; ++g)
        ox[(row0 + 16 * b + kg * 4 + g) * Nn + n] = x[b][t][g];
  }
#pragma unroll
  for (int i = 0; i < 3; ++i) {
    int m = (3 * w + i) * 16 + fr;
#pragma unroll
    for (int b = 0; b < 2; ++b)
#pragma unroll
      for (int g = 0; g < 4; ++g) {
        int r = row0 + 16 * b + kg * 4 + g;
        if (m < M1n) oy1[r * M1n + m] = ys[b][i][g];
        else         oy2[r * M2n + (m - M1n)] = ys[b][i][g];
      }
  }
}

extern "C" void kernel_launch(void* const* d_in, const int* in_sizes, int n_in,
                              void* d_out, int out_size, void* d_ws, size_t ws_size,
                              hipStream_t stream) {
  const float* x0  = (const float*)d_in[0];
  const float* y10 = (const float*)d_in[1];
  const float* y20 = (const float*)d_in[2];
  const float* z   = (const float*)d_in[3];
  const float* c   = (const float*)d_in[4];
  const float* A1  = (const float*)d_in[5];
  const float* A2  = (const float*)d_in[6];

  ushort* Arm = (ushort*)d_ws;          // 192*256 bf16
  ushort* AT  = Arm + Mn * Nn;          // 256*192 bf16

  prep_kernel<<<(Mn * Nn + 255) / 256, 256, 0, stream>>>(A1, A2, Arm, AT);
  pdhg_kernel<<<Bn / 32, 256, 0, stream>>>(x0, y10, y20, z, c, Arm, AT, (float*)d_out);
}

// Round 7
// 74.131 us; speedup vs baseline: 1.1642x; 1.1642x over previous
//
#include <hip/hip_runtime.h>

typedef __attribute__((ext_vector_type(8))) __bf16 bf16x8;
typedef __attribute__((ext_vector_type(4))) float f32x4;
typedef __attribute__((ext_vector_type(4))) int i32x4;

constexpr int Bn = 8192, Nn = 256, M1n = 128, M2n = 64, Mn = 192, ITERS = 30;
constexpr float TAUc = 0.05f, SIGc = 0.05f;

__device__ __forceinline__ ushort f2bf(float f) {
  unsigned u = __builtin_bit_cast(unsigned, f);
  u = (u + 0x7FFFu + ((u >> 16) & 1u)) >> 16;
  return (ushort)u;
}

// packed f32->bf16 (RNE), 2 values per instruction
__device__ __forceinline__ unsigned cvtpk(float lo, float hi) {
  unsigned r;
  asm("v_cvt_pk_bf16_f32 %0, %1, %2" : "=v"(r) : "v"(lo), "v"(hi));
  return r;
}

// Pin a fragment into AGPRs: volatile asm result cannot be rematerialized, and
// the AGPR file has no pressure from ordinary VALU code, so it stays resident.
__device__ __forceinline__ void pina(i32x4& v) { asm volatile("" : "+a"(v)); }

// Builtin MFMA (hazard-safe) with an AGPR-pinned B fragment.
__device__ __forceinline__ f32x4 mfma_b(bf16x8 a, i32x4 bfrag, f32x4 acc) {
  return __builtin_amdgcn_mfma_f32_16x16x32_bf16(
      a, __builtin_bit_cast(bf16x8, bfrag), acc, 0, 0, 0);
}

// Build bf16 copies of A = [A1;A2] in both orientations:
// Arm[m][n] (192x256 row-major), AT[n][m] (256x192 row-major).
__global__ void prep_kernel(const float* __restrict__ A1, const float* __restrict__ A2,
                            ushort* __restrict__ Arm, ushort* __restrict__ AT) {
  int i = blockIdx.x * 256 + threadIdx.x;
  if (i >= Mn * Nn) return;
  int m = i / Nn, n = i % Nn;
  float v = (m < M1n) ? A1[m * Nn + n] : A2[(m - M1n) * Nn + n];
  ushort b = f2bf(v);
  Arm[m * Nn + n] = b;
  AT[n * Mn + m] = b;
}

// 8 waves per block, 32 rows (2 bands of 16). grid = 256 = 1 block/CU = 2 waves/SIMD.
// GEMM-1 units of wave w: u0=(band0, m=16w+fr, relu), u1=(band1, same m, relu),
//                         u2=(band w>>2, m=128+16*(w&3)+fr, linear)  -> 24 MFMA.
// GEMM-3 units: n-tiles {2w,2w+1} x both bands -> 24 MFMA.
// 28 A-fragments pinned in AGPRs (112); x, y, sigma*z state in registers.
__global__ __launch_bounds__(512, 2) void pdhg_kernel(
    const float* __restrict__ x0, const float* __restrict__ y10,
    const float* __restrict__ y20, const float* __restrict__ z,
    const float* __restrict__ c, const ushort* __restrict__ Arm,
    const ushort* __restrict__ AT, float* __restrict__ out) {
  __shared__ __align__(16) ushort xb_lds[2][16][264];  // xbar bands (bf16)
  __shared__ __align__(16) ushort y_lds[2][16][200];   // y bands (bf16)

  const int lane = threadIdx.x & 63;
  const int w = threadIdx.x >> 6;     // wave 0..7
  const int fr = lane & 15;           // fragment row (A-op) / col (B-op, C/D)
  const int kg = lane >> 4;           // k-group 0..3
  const int row0 = blockIdx.x * 32;   // 32-row super-band

  const int m01 = w * 16 + fr;              // y1 column (units 0,1)
  const int m2 = M1n + (w & 3) * 16 + fr;   // y2 column (unit 2)
  const int bu2 = w >> 2;                   // band of unit 2
  const int nA = (2 * w) * 16 + fr;         // n-tile 2w
  const int nB = (2 * w + 1) * 16 + fr;     // n-tile 2w+1

  float x[2][2][4];             // [tile t][band b][g]
  float yu[3][4], zu[3][4];     // y and sigma*z per GEMM-1 unit
  const float cvA = c[nA], cvB = c[nB];

  // ---- init x state + initial xbar = x0 into LDS (2 n-tiles x 2 bands)
#pragma unroll
  for (int t = 0; t < 2; ++t) {
    const int n = t ? nB : nA;
#pragma unroll
    for (int b = 0; b < 2; ++b)
#pragma unroll
      for (int g = 0; g < 4; ++g) {
        float v = x0[(row0 + 16 * b + kg * 4 + g) * Nn + n];
        x[t][b][g] = v;
        xb_lds[b][kg * 4 + g][n] = f2bf(v);
      }
  }
  // ---- init y, sigma*z state (registers)
#pragma unroll
  for (int g = 0; g < 4; ++g) {
    int r0 = row0 + kg * 4 + g;        // unit 0 row (band 0)
    int r1 = r0 + 16;                  // unit 1 row (band 1)
    int r2 = row0 + 16 * bu2 + kg * 4 + g;  // unit 2 row
    zu[0][g] = SIGc * z[r0 * Mn + m01];  yu[0][g] = y10[r0 * M1n + m01];
    zu[1][g] = SIGc * z[r1 * Mn + m01];  yu[1][g] = y10[r1 * M1n + m01];
    zu[2][g] = SIGc * z[r2 * Mn + m2];   yu[2][g] = y20[r2 * M2n + (m2 - M1n)];
  }

  // ---- preload loop-invariant A fragments into AGPRs (28 frags = 112 AGPR)
  i32x4 armF01[8], armF2[8], atFA[6], atFB[6];
#pragma unroll
  for (int kf = 0; kf < 8; ++kf) {
    armF01[kf] = *reinterpret_cast<const i32x4*>(&Arm[m01 * Nn + kf * 32 + kg * 8]); pina(armF01[kf]);
    armF2[kf]  = *reinterpret_cast<const i32x4*>(&Arm[m2 * Nn + kf * 32 + kg * 8]);  pina(armF2[kf]);
  }
#pragma unroll
  for (int kf = 0; kf < 6; ++kf) {
    atFA[kf] = *reinterpret_cast<const i32x4*>(&AT[nA * Mn + kf * 32 + kg * 8]); pina(atFA[kf]);
    atFB[kf] = *reinterpret_cast<const i32x4*>(&AT[nB * Mn + kf * 32 + kg * 8]); pina(atFB[kf]);
  }

  __syncthreads();

  for (int it = 0; it < ITERS; ++it) {
    // ---- GEMM-1: S = xbar @ A^T (3 units, branchless; fx streamed from LDS)
    f32x4 a0 = {0.f, 0.f, 0.f, 0.f}, a1 = a0, a2 = a0;
#pragma unroll
    for (int kf = 0; kf < 8; ++kf) {
      bf16x8 f0 = *reinterpret_cast<const bf16x8*>(&xb_lds[0][fr][kf * 32 + kg * 8]);
      bf16x8 f1 = *reinterpret_cast<const bf16x8*>(&xb_lds[1][fr][kf * 32 + kg * 8]);
      bf16x8 f2 = *reinterpret_cast<const bf16x8*>(&xb_lds[bu2][fr][kf * 32 + kg * 8]);
      a0 = mfma_b(f0, armF01[kf], a0);
      a1 = mfma_b(f1, armF01[kf], a1);
      a2 = mfma_b(f2, armF2[kf], a2);
    }

    // ---- y update (f32 reg state), write bf16 Y bands to LDS
#pragma unroll
    for (int g = 0; g < 4; ++g) {
      yu[0][g] = fmaxf(__builtin_fmaf(SIGc, a0[g], yu[0][g]) - zu[0][g], 0.f);
      yu[1][g] = fmaxf(__builtin_fmaf(SIGc, a1[g], yu[1][g]) - zu[1][g], 0.f);
      yu[2][g] = __builtin_fmaf(SIGc, a2[g], yu[2][g]) - zu[2][g];  // linear (y2)
    }
    {
      unsigned p01 = cvtpk(yu[0][0], yu[0][1]), p23 = cvtpk(yu[0][2], yu[0][3]);
      y_lds[0][kg * 4 + 0][m01] = (ushort)p01;
      y_lds[0][kg * 4 + 1][m01] = (ushort)(p01 >> 16);
      y_lds[0][kg * 4 + 2][m01] = (ushort)p23;
      y_lds[0][kg * 4 + 3][m01] = (ushort)(p23 >> 16);
    }
    {
      unsigned p01 = cvtpk(yu[1][0], yu[1][1]), p23 = cvtpk(yu[1][2], yu[1][3]);
      y_lds[1][kg * 4 + 0][m01] = (ushort)p01;
      y_lds[1][kg * 4 + 1][m01] = (ushort)(p01 >> 16);
      y_lds[1][kg * 4 + 2][m01] = (ushort)p23;
      y_lds[1][kg * 4 + 3][m01] = (ushort)(p23 >> 16);
    }
    {
      unsigned p01 = cvtpk(yu[2][0], yu[2][1]), p23 = cvtpk(yu[2][2], yu[2][3]);
      y_lds[bu2][kg * 4 + 0][m2] = (ushort)p01;
      y_lds[bu2][kg * 4 + 1][m2] = (ushort)(p01 >> 16);
      y_lds[bu2][kg * 4 + 2][m2] = (ushort)p23;
      y_lds[bu2][kg * 4 + 3][m2] = (ushort)(p23 >> 16);
    }
    __syncthreads();

    // ---- GEMM-3: G = y @ A (2 n-tiles x 2 bands; fy streamed from LDS)
    f32x4 b00 = {0.f, 0.f, 0.f, 0.f}, b01 = b00, b10 = b00, b11 = b00;  // b{band}{t}
#pragma unroll
    for (int kf = 0; kf < 6; ++kf) {
      bf16x8 g0 = *reinterpret_cast<const bf16x8*>(&y_lds[0][fr][kf * 32 + kg * 8]);
      bf16x8 g1 = *reinterpret_cast<const bf16x8*>(&y_lds[1][fr][kf * 32 + kg * 8]);
      b00 = mfma_b(g0, atFA[kf], b00);
      b01 = mfma_b(g0, atFB[kf], b01);
      b10 = mfma_b(g1, atFA[kf], b10);
      b11 = mfma_b(g1, atFB[kf], b11);
    }

    // ---- x update (f32 reg state), write bf16 xbar to LDS
    const bool notlast = (it != ITERS - 1);
#pragma unroll
    for (int t = 0; t < 2; ++t) {
      const int n = t ? nB : nA;
      const float cv = t ? cvB : cvA;
#pragma unroll
      for (int b = 0; b < 2; ++b) {
        const f32x4 bt = (t == 0) ? (b == 0 ? b00 : b10) : (b == 0 ? b01 : b11);
        float xb[4];
#pragma unroll
        for (int g = 0; g < 4; ++g) {
          float grad = cv + bt[g];
          float xn = fmaxf(__builtin_fmaf(-TAUc, grad, x[t][b][g]), 0.f);
          xb[g] = 2.f * xn - x[t][b][g];  // theta = 1
          x[t][b][g] = xn;
        }
        if (notlast) {
          unsigned p01 = cvtpk(xb[0], xb[1]), p23 = cvtpk(xb[2], xb[3]);
          xb_lds[b][kg * 4 + 0][n] = (ushort)p01;
          xb_lds[b][kg * 4 + 1][n] = (ushort)(p01 >> 16);
          xb_lds[b][kg * 4 + 2][n] = (ushort)p23;
          xb_lds[b][kg * 4 + 3][n] = (ushort)(p23 >> 16);
        }
      }
    }
    if (notlast) __syncthreads();
  }

  // ---- store outputs: x (B x 256), y1 (B x 128), y2 (B x 64), all f32
  float* ox = out;
  float* oy1 = out + Bn * Nn;
  float* oy2 = oy1 + Bn * M1n;
#pragma unroll
  for (int t = 0; t < 2; ++t) {
    const int n = t ? nB : nA;
#pragma unroll
    for (int b = 0; b < 2; ++b)
#pragma unroll
      for (int g = 0; g < 4; ++g)
        ox[(row0 + 16 * b + kg * 4 + g) * Nn + n] = x[t][b][g];
  }
#pragma unroll
  for (int g = 0; g < 4; ++g) {
    int r0 = row0 + kg * 4 + g;
    oy1[r0 * M1n + m01] = yu[0][g];
    oy1[(r0 + 16) * M1n + m01] = yu[1][g];
    oy2[(row0 + 16 * bu2 + kg * 4 + g) * M2n + (m2 - M1n)] = yu[2][g];
  }
}

extern "C" void kernel_launch(void* const* d_in, const int* in_sizes, int n_in,
                              void* d_out, int out_size, void* d_ws, size_t ws_size,
                              hipStream_t stream) {
  const float* x0  = (const float*)d_in[0];
  const float* y10 = (const float*)d_in[1];
  const float* y20 = (const float*)d_in[2];
  const float* z   = (const float*)d_in[3];
  const float* c   = (const float*)d_in[4];
  const float* A1  = (const float*)d_in[5];
  const float* A2  = (const float*)d_in[6];

  ushort* Arm = (ushort*)d_ws;          // 192*256 bf16
  ushort* AT  = Arm + Mn * Nn;          // 256*192 bf16

  prep_kernel<<<(Mn * Nn + 255) / 256, 256, 0, stream>>>(A1, A2, Arm, AT);
  pdhg_kernel<<<Bn / 32, 512, 0, stream>>>(x0, y10, y20, z, c, Arm, AT, (float*)d_out);
}

// Round 8
// 67.695 us; speedup vs baseline: 1.2749x; 1.0951x over previous
//
#include <hip/hip_runtime.h>

typedef __attribute__((ext_vector_type(8))) __bf16 bf16x8;
typedef __attribute__((ext_vector_type(4))) float f32x4;
typedef __attribute__((ext_vector_type(4))) int i32x4;

constexpr int Bn = 8192, Nn = 256, M1n = 128, M2n = 64, Mn = 192, ITERS = 30;
constexpr float TAUc = 0.05f, SIGc = 0.05f;

__device__ __forceinline__ ushort f2bf(float f) {
  unsigned u = __builtin_bit_cast(unsigned, f);
  u = (u + 0x7FFFu + ((u >> 16) & 1u)) >> 16;
  return (ushort)u;
}

// packed f32->bf16 (RNE), 2 values per instruction
__device__ __forceinline__ unsigned cvtpk(float lo, float hi) {
  unsigned r;
  asm("v_cvt_pk_bf16_f32 %0, %1, %2" : "=v"(r) : "v"(lo), "v"(hi));
  return r;
}

// Pin a fragment into AGPRs: volatile asm result, cannot be rematerialized.
__device__ __forceinline__ void pina(i32x4& v) { asm volatile("" : "+a"(v)); }

// SWAPPED builtin MFMA: A-operand = pinned A-matrix fragment, B-operand = the
// LDS-streamed x/y fragment. Output: lane(fr,kg) reg g = D[col=fr batch row]
// [row = tile*16 + kg*4 + g]  -> 4 consecutive m/n per lane.
__device__ __forceinline__ f32x4 mfma_swp(i32x4 afrag, bf16x8 b, f32x4 acc) {
  return __builtin_amdgcn_mfma_f32_16x16x32_bf16(
      __builtin_bit_cast(bf16x8, afrag), b, acc, 0, 0, 0);
}

// Build bf16 copies of A = [A1;A2] in both orientations:
// Arm[m][n] (192x256 row-major), AT[n][m] (256x192 row-major).
__global__ void prep_kernel(const float* __restrict__ A1, const float* __restrict__ A2,
                            ushort* __restrict__ Arm, ushort* __restrict__ AT) {
  int i = blockIdx.x * 256 + threadIdx.x;
  if (i >= Mn * Nn) return;
  int m = i / Nn, n = i % Nn;
  float v = (m < M1n) ? A1[m * Nn + n] : A2[(m - M1n) * Nn + n];
  ushort b = f2bf(v);
  Arm[m * Nn + n] = b;
  AT[n * Mn + m] = b;
}

// 8 waves, 32 rows (2 bands). grid = 256 = 1 block/CU, 2 waves/SIMD.
// GEMM-1 (band-split): wave w -> band w&1, m-tiles {3*(w>>1)+0..2}; reads ONE
//   band's xbar (8 ds_read_b128). 24 armF frags in AGPR.
// GEMM-3: n-tiles {2w,2w+1} x both bands; 12 atF frags in AGPR. Total 144 AGPR.
// Swapped-operand outputs -> all LDS writes ds_write_b64, global I/O dwordx4.
__global__ __launch_bounds__(512, 2) void pdhg_kernel(
    const float* __restrict__ x0, const float* __restrict__ y10,
    const float* __restrict__ y20, const float* __restrict__ z,
    const float* __restrict__ c, const ushort* __restrict__ Arm,
    const ushort* __restrict__ AT, float* __restrict__ out) {
  __shared__ __align__(16) ushort xb_lds[2][16][264];  // xbar bands (bf16)
  __shared__ __align__(16) ushort y_lds[2][16][200];   // y bands (bf16)

  const int lane = threadIdx.x & 63;
  const int w = threadIdx.x >> 6;     // wave 0..7
  const int fr = lane & 15;           // batch row within band (output col)
  const int kg = lane >> 4;           // k-group / output row-quad
  const int row0 = blockIdx.x * 32;   // 32-row super-band

  const int b1 = w & 1;               // GEMM-1 band
  const int mg = w >> 1;              // GEMM-1 m-tile group: tiles 3mg..3mg+2
  const int rG1 = row0 + 16 * b1 + fr;  // GEMM-1 batch row of this lane

  float x[2][2][4];     // [n-tile t][band b][g]
  float cv[2][4];
  float ys[3][4], zs[3][4];

  // ---- init x state (dwordx4) + initial xbar into LDS (b64)
#pragma unroll
  for (int t = 0; t < 2; ++t) {
    const int n0 = (2 * w + t) * 16 + kg * 4;
    *reinterpret_cast<f32x4*>(cv[t]) = *reinterpret_cast<const f32x4*>(&c[n0]);
#pragma unroll
    for (int b = 0; b < 2; ++b) {
      f32x4 v = *reinterpret_cast<const f32x4*>(&x0[(row0 + 16 * b + fr) * Nn + n0]);
#pragma unroll
      for (int g = 0; g < 4; ++g) x[t][b][g] = v[g];
      uint2 p = make_uint2(cvtpk(v[0], v[1]), cvtpk(v[2], v[3]));
      *reinterpret_cast<uint2*>(&xb_lds[b][fr][n0]) = p;
    }
  }
  // ---- init y, sigma*z state (dwordx4; band b1 only)
#pragma unroll
  for (int i = 0; i < 3; ++i) {
    const int mt = 3 * mg + i;
    const int m0 = mt * 16 + kg * 4;
    f32x4 zv = *reinterpret_cast<const f32x4*>(&z[rG1 * Mn + m0]);
    f32x4 yv = (mt < 8) ? *reinterpret_cast<const f32x4*>(&y10[rG1 * M1n + m0])
                        : *reinterpret_cast<const f32x4*>(&y20[rG1 * M2n + (m0 - M1n)]);
#pragma unroll
    for (int g = 0; g < 4; ++g) { zs[i][g] = SIGc * zv[g]; ys[i][g] = yv[g]; }
  }

  // ---- preload loop-invariant A fragments into AGPRs (36 frags = 144 AGPR)
  i32x4 armF[3][8], atF[2][6];
#pragma unroll
  for (int i = 0; i < 3; ++i) {
    const int m = (3 * mg + i) * 16 + fr;
#pragma unroll
    for (int kf = 0; kf < 8; ++kf) {
      armF[i][kf] = *reinterpret_cast<const i32x4*>(&Arm[m * Nn + kf * 32 + kg * 8]);
      pina(armF[i][kf]);
    }
  }
#pragma unroll
  for (int t = 0; t < 2; ++t) {
    const int n = (2 * w + t) * 16 + fr;
#pragma unroll
    for (int kf = 0; kf < 6; ++kf) {
      atF[t][kf] = *reinterpret_cast<const i32x4*>(&AT[n * Mn + kf * 32 + kg * 8]);
      pina(atF[t][kf]);
    }
  }

  __syncthreads();

  for (int it = 0; it < ITERS; ++it) {
    // ---- GEMM-1: band b1 only; fx streamed (8 reads), 3 m-tile chains
    f32x4 a0 = {0.f, 0.f, 0.f, 0.f}, a1 = a0, a2 = a0;
#pragma unroll
    for (int kf = 0; kf < 8; ++kf) {
      bf16x8 fx = *reinterpret_cast<const bf16x8*>(&xb_lds[b1][fr][kf * 32 + kg * 8]);
      a0 = mfma_swp(armF[0][kf], fx, a0);
      a1 = mfma_swp(armF[1][kf], fx, a1);
      a2 = mfma_swp(armF[2][kf], fx, a2);
    }

    // ---- y update; write bf16 Y (one ds_write_b64 per tile)
#pragma unroll
    for (int i = 0; i < 3; ++i) {
      const int mt = 3 * mg + i;
      const int m0 = mt * 16 + kg * 4;
      const f32x4 ai = (i == 0) ? a0 : (i == 1) ? a1 : a2;
      const bool relu = (mt < 8);
#pragma unroll
      for (int g = 0; g < 4; ++g) {
        float s = __builtin_fmaf(SIGc, ai[g], ys[i][g]) - zs[i][g];
        ys[i][g] = relu ? fmaxf(s, 0.f) : s;
      }
      uint2 p = make_uint2(cvtpk(ys[i][0], ys[i][1]), cvtpk(ys[i][2], ys[i][3]));
      *reinterpret_cast<uint2*>(&y_lds[b1][fr][m0]) = p;
    }
    __syncthreads();

    // ---- GEMM-3: both bands, 2 n-tiles; fy streamed (12 reads), 4 chains
    f32x4 q00 = {0.f, 0.f, 0.f, 0.f}, q01 = q00, q10 = q00, q11 = q00;  // q{band}{t}
#pragma unroll
    for (int kf = 0; kf < 6; ++kf) {
      bf16x8 g0 = *reinterpret_cast<const bf16x8*>(&y_lds[0][fr][kf * 32 + kg * 8]);
      bf16x8 g1 = *reinterpret_cast<const bf16x8*>(&y_lds[1][fr][kf * 32 + kg * 8]);
      q00 = mfma_swp(atF[0][kf], g0, q00);
      q01 = mfma_swp(atF[1][kf], g0, q01);
      q10 = mfma_swp(atF[0][kf], g1, q10);
      q11 = mfma_swp(atF[1][kf], g1, q11);
    }

    // ---- x update; write bf16 xbar (one ds_write_b64 per tile x band)
    const bool notlast = (it != ITERS - 1);
#pragma unroll
    for (int t = 0; t < 2; ++t) {
      const int n0 = (2 * w + t) * 16 + kg * 4;
#pragma unroll
      for (int b = 0; b < 2; ++b) {
        const f32x4 qt = (t == 0) ? (b == 0 ? q00 : q10) : (b == 0 ? q01 : q11);
        float xb[4];
#pragma unroll
        for (int g = 0; g < 4; ++g) {
          float grad = cv[t][g] + qt[g];
          float xn = fmaxf(__builtin_fmaf(-TAUc, grad, x[t][b][g]), 0.f);
          xb[g] = 2.f * xn - x[t][b][g];  // theta = 1
          x[t][b][g] = xn;
        }
        if (notlast) {
          uint2 p = make_uint2(cvtpk(xb[0], xb[1]), cvtpk(xb[2], xb[3]));
          *reinterpret_cast<uint2*>(&xb_lds[b][fr][n0]) = p;
        }
      }
    }
    if (notlast) __syncthreads();
  }

  // ---- store outputs (all dwordx4): x (Bx256), y1 (Bx128), y2 (Bx64)
  float* ox = out;
  float* oy1 = out + Bn * Nn;
  float* oy2 = oy1 + Bn * M1n;
#pragma unroll
  for (int t = 0; t < 2; ++t) {
    const int n0 = (2 * w + t) * 16 + kg * 4;
#pragma unroll
    for (int b = 0; b < 2; ++b) {
      f32x4 v;
#pragma unroll
      for (int g = 0; g < 4; ++g) v[g] = x[t][b][g];
      *reinterpret_cast<f32x4*>(&ox[(row0 + 16 * b + fr) * Nn + n0]) = v;
    }
  }
#pragma unroll
  for (int i = 0; i < 3; ++i) {
    const int mt = 3 * mg + i;
    const int m0 = mt * 16 + kg * 4;
    f32x4 v;
#pragma unroll
    for (int g = 0; g < 4; ++g) v[g] = ys[i][g];
    if (mt < 8) *reinterpret_cast<f32x4*>(&oy1[rG1 * M1n + m0]) = v;
    else        *reinterpret_cast<f32x4*>(&oy2[rG1 * M2n + (m0 - M1n)]) = v;
  }
}

extern "C" void kernel_launch(void* const* d_in, const int* in_sizes, int n_in,
                              void* d_out, int out_size, void* d_ws, size_t ws_size,
                              hipStream_t stream) {
  const float* x0  = (const float*)d_in[0];
  const float* y10 = (const float*)d_in[1];
  const float* y20 = (const float*)d_in[2];
  const float* z   = (const float*)d_in[3];
  const float* c   = (const float*)d_in[4];
  const float* A1  = (const float*)d_in[5];
  const float* A2  = (const float*)d_in[6];

  ushort* Arm = (ushort*)d_ws;          // 192*256 bf16
  ushort* AT  = Arm + Mn * Nn;          // 256*192 bf16

  prep_kernel<<<(Mn * Nn + 255) / 256, 256, 0, stream>>>(A1, A2, Arm, AT);
  pdhg_kernel<<<Bn / 32, 512, 0, stream>>>(x0, y10, y20, z, c, Arm, AT, (float*)d_out);
}